// Round 1
// baseline (403.155 us; speedup 1.0000x reference)
//
#include <hip/hip_runtime.h>
#include <math.h>

#define TT 512
#define BB 32
#define SS 64
#define AA 8
#define DD 32
#define EPSF 1e-6f
#define SEPS (64.0f * 1e-6f)   // reference adds EPS under the 64-term i-sum
#define TS 68                  // tile row stride (floats): 16B aligned, breaks pow2

__device__ __forceinline__ int   f2i(float x){ return __float_as_int(x); }
__device__ __forceinline__ float i2f(int x){ return __int_as_float(x); }
__device__ __forceinline__ float readlane_f(float v, int l){
  return i2f(__builtin_amdgcn_readlane(f2i(v), l));
}
// DPP add stage: ctrl/rmask must be compile-time constants -> template params
template<int CTRL, int RMASK>
__device__ __forceinline__ float dpp_add(float x){
  return x + i2f(__builtin_amdgcn_update_dpp(0, f2i(x), CTRL, RMASK, 0xf, true));
}
// full 64-lane sum via DPP (VALU only, no LDS pipe), broadcast via readlane 63
__device__ __forceinline__ float wave_sum_dpp(float x){
  x = dpp_add<0x111, 0xf>(x);  // row_shr:1
  x = dpp_add<0x112, 0xf>(x);  // row_shr:2
  x = dpp_add<0x114, 0xf>(x);  // row_shr:4
  x = dpp_add<0x118, 0xf>(x);  // row_shr:8
  x = dpp_add<0x142, 0xa>(x);  // row_bcast:15 -> rows 1,3
  x = dpp_add<0x143, 0xc>(x);  // row_bcast:31 -> rows 2,3
  return readlane_f(x, 63);
}
// shuffle helpers for the small parallel kernels (latency hidden by occupancy)
__device__ __forceinline__ float wave_sum(float v){
  #pragma unroll
  for (int m = 1; m < 64; m <<= 1) v += __shfl_xor(v, m, 64);
  return v;
}
__device__ __forceinline__ float wave_max(float v){
  #pragma unroll
  for (int m = 1; m < 64; m <<= 1) v = fmaxf(v, __shfl_xor(v, m, 64));
  return v;
}
// raw barrier: drains LDS only; global prefetch loads stay in flight
#define BARRIER() asm volatile("s_waitcnt lgkmcnt(0)\n\ts_barrier" ::: "memory")

// --- kernel 0: invvar = exp(-logv), cs[s] = sum_d logv + D*log(2pi)
__global__ void prep_kernel(const float* __restrict__ logv,
                            float* __restrict__ iv, float* __restrict__ cs){
  int gid = blockIdx.x * blockDim.x + threadIdx.x;
  if (gid < SS * DD) iv[gid] = __expf(-logv[gid]);
  if (gid < SS){
    float s = 0.f;
    #pragma unroll
    for (int d = 0; d < DD; ++d) s += logv[gid * DD + d];
    cs[gid] = s + (float)DD * 1.8378770664093453f;
  }
}

// --- kernel 1: slx[t,b,s] = lx - rowmax(lx)
__global__ __launch_bounds__(256) void logpx_kernel(
    const float* __restrict__ x, const float* __restrict__ mu,
    const float* __restrict__ iv, const float* __restrict__ cs,
    float* __restrict__ slx_out){
  const int lane = threadIdx.x & 63;
  const int w = threadIdx.x >> 6;
  const int row = blockIdx.x * 4 + w;
  const float* __restrict__ xp  = x  + row * DD;
  const float* __restrict__ mup = mu + lane * DD;
  const float* __restrict__ ivp = iv + lane * DD;
  float acc = 0.f;
  #pragma unroll
  for (int d = 0; d < DD; ++d){
    float diff = xp[d] - mup[d];
    acc = fmaf(diff * diff, ivp[d], acc);
  }
  float lx = -0.5f * (acc + cs[lane]);
  float mx = wave_max(lx);
  slx_out[row * SS + lane] = lx - mx;
}

// --- kernel T: precompute row-normalized transition tiles for all (t,b).
// trans[t][b][i][j] = softmax_j( w_base[i][j] + sum_k a[t,b,k] w_act[k][i][j] )
// Fully parallel: spreads the tile-gen VALU work (which was serialized on 64
// CUs inside the scan) across all 256 CUs.
__global__ __launch_bounds__(512) void trans_kernel(
    const float* __restrict__ a, const float* __restrict__ w_base,
    const float* __restrict__ w_act, float* __restrict__ trans){
  const int b  = blockIdx.x >> 4;       // 32 b  x 16 t-chunks
  const int tc = blockIdx.x & 15;
  const int t0 = tc * 32;
  const int tid = threadIdx.x;
  const int i  = tid >> 3;              // row 0..63
  const int j0 = (tid & 7) * 8;         // 8 cols per thread
  __shared__ float aS[32 * 8];
  if (tid < 256)
    aS[tid] = a[(((t0 + (tid >> 3)) * BB) + b) * AA + (tid & 7)];
  float wb[8], wa[8][8];
  #pragma unroll
  for (int jj = 0; jj < 8; ++jj){
    wb[jj] = w_base[i * SS + j0 + jj];
    #pragma unroll
    for (int k = 0; k < 8; ++k)
      wa[k][jj] = w_act[(k * SS + i) * SS + j0 + jj];
  }
  __syncthreads();
  const int nt = ((TT - 1) - t0 < 32) ? ((TT - 1) - t0) : 32;
  for (int tt = 0; tt < nt; ++tt){
    float aa[8];
    #pragma unroll
    for (int k = 0; k < 8; ++k) aa[k] = aS[tt * 8 + k];
    float ev[8]; float rs = 0.f;
    #pragma unroll
    for (int jj = 0; jj < 8; ++jj){
      float u = wb[jj];
      #pragma unroll
      for (int k = 0; k < 8; ++k) u = fmaf(aa[k], wa[k][jj], u);
      ev[jj] = __expf(u); rs += ev[jj];
    }
    // full row sum: 8 threads (lanes differing in bits 0..2) share row i
    rs += __shfl_xor(rs, 1, 64);
    rs += __shfl_xor(rs, 2, 64);
    rs += __shfl_xor(rs, 4, 64);
    float rinv = __builtin_amdgcn_rcpf(rs);
    float* __restrict__ op = trans + ((size_t)(t0 + tt) * BB + b) * (SS * SS)
                           + i * SS + j0;
    *(float4*)op       = make_float4(ev[0]*rinv, ev[1]*rinv, ev[2]*rinv, ev[3]*rinv);
    *(float4*)(op + 4) = make_float4(ev[4]*rinv, ev[5]*rinv, ev[6]*rinv, ev[7]*rinv);
  }
}

// --- kernel 2 (new): fused pipelined scans, tiles STREAMED from global.
// blocks [0,B): fwd; [B,2B): bwd. 512 thr = 8 waves: waves 0-3 consumers,
// waves 4-7 producers (load tile s+1 into 3-deep LDS ring; global loads
// register-pipelined 2 iterations ahead, parity double-buffer, no copies).
// Tiles are pre-normalized -> rsp rowsum machinery deleted from consumers.
__global__ __launch_bounds__(512) void scan_pre_kernel(
    const float* __restrict__ slx, const float* __restrict__ mask,
    const float* __restrict__ il, const float* __restrict__ trans,
    float* __restrict__ alpha, float* __restrict__ log_beta){
  const int lane = threadIdx.x & 63;
  const int w    = threadIdx.x >> 6;
  const bool is_fwd = (blockIdx.x < BB);
  const int b = is_fwd ? blockIdx.x : (blockIdx.x - BB);

  __shared__ __align__(16) float tile[3][SS * TS];  // normalized tr, [i][j]
  __shared__ float fpart[2][4][SS];                 // consumer matvec partials
  __shared__ float mLDS[TT];                        // mask[:, b] staged

  for (int idx = threadIdx.x; idx < TT; idx += 512)
    mLDS[idx] = mask[idx * BB + b];

  if (w >= 4){
    // ======================= PRODUCERS (streamers) =======================
    const int pw = w - 4;                                   // 0..3
    const size_t thofs  = (size_t)pw * 1024 + (size_t)lane * 16; // floats
    const int    ldsoff = (pw * 16 + (lane >> 2)) * TS + (lane & 3) * 16;
    const size_t tstride = (size_t)BB * SS * SS;
    const float* gb = trans + (size_t)b * (SS * SS) + thofs;
    const long gstep = is_fwd ? (long)tstride : -(long)tstride;
    const float* g0 = is_fwd ? gb : (gb + (size_t)(TT - 2) * tstride);
    float4 A0,A1,A2,A3, B0,B1,B2,B3;
    { // prologue: tile t(0) -> slot 0 now; t(1)->A (iter 0); t(2)->B (iter 1)
      const float4* gp = (const float4*)g0;
      float4 c0 = gp[0], c1 = gp[1], c2 = gp[2], c3 = gp[3];
      const float4* ga = (const float4*)(g0 + gstep);
      A0 = ga[0]; A1 = ga[1]; A2 = ga[2]; A3 = ga[3];
      const float4* gbp = (const float4*)(g0 + 2 * gstep);
      B0 = gbp[0]; B1 = gbp[1]; B2 = gbp[2]; B3 = gbp[3];
      float* tp = &tile[0][ldsoff];
      *(float4*)tp = c0; *(float4*)(tp+4) = c1;
      *(float4*)(tp+8) = c2; *(float4*)(tp+12) = c3;
    }
    const float* gcur = g0 + 3 * gstep;
    BARRIER();
    int tw = 1;
    for (int s = 0; s < TT - 1; ++s){
      if (s <= TT - 3){
        float* tp = &tile[tw][ldsoff];
        if ((s & 1) == 0){
          *(float4*)tp = A0; *(float4*)(tp+4) = A1;
          *(float4*)(tp+8) = A2; *(float4*)(tp+12) = A3;
          if (s <= TT - 5){
            const float4* gp = (const float4*)gcur;
            A0 = gp[0]; A1 = gp[1]; A2 = gp[2]; A3 = gp[3];
            gcur += gstep;
          }
        } else {
          *(float4*)tp = B0; *(float4*)(tp+4) = B1;
          *(float4*)(tp+8) = B2; *(float4*)(tp+12) = B3;
          if (s <= TT - 5){
            const float4* gp = (const float4*)gcur;
            B0 = gp[0]; B1 = gp[1]; B2 = gp[2]; B3 = gp[3];
            gcur += gstep;
          }
        }
        tw = (tw == 2) ? 0 : tw + 1;
      }
      BARRIER();
    }
  } else if (is_fwd){
    // ==================== FORWARD CONSUMERS ====================
    const int wb16 = __builtin_amdgcn_readfirstlane(w * 16);
    float u = __expf(slx[b * SS + lane] + il[lane]);     // unnormalized alpha_0
    float c = __builtin_amdgcn_rcpf(wave_sum_dpp(u));
    if (w == 0) alpha[b * SS + lane] = u * c;
    float slxn = slx[(BB + b) * SS + lane];              // slx[t=1]
    float elxc = 0.f;
    BARRIER();
    int ts = 0;
    for (int s = 0; s < TT - 1; ++s){
      if (s > 0){
        const int fs = (s - 1) & 1;
        float S = (fpart[fs][0][lane] + fpart[fs][1][lane])
                + (fpart[fs][2][lane] + fpart[fs][3][lane]);
        u = elxc * fmaf(c, S, SEPS);                     // alpha_s (unnormalized)
        c = __builtin_amdgcn_rcpf(wave_sum_dpp(u));      // off critical path (DPP)
        if (w == 0) alpha[(s * BB + b) * SS + lane] = u * c;
      }
      float va = u;                                      // tiles pre-normalized
      const float* __restrict__ tp = &tile[ts][0];
      float a0 = 0.f, a1 = 0.f, a2 = 0.f, a3 = 0.f;
      #pragma unroll
      for (int r = 0; r < 16; r += 4){
        a0 = fmaf(readlane_f(va, wb16 + r    ), tp[(wb16 + r    ) * TS + lane], a0);
        a1 = fmaf(readlane_f(va, wb16 + r + 1), tp[(wb16 + r + 1) * TS + lane], a1);
        a2 = fmaf(readlane_f(va, wb16 + r + 2), tp[(wb16 + r + 2) * TS + lane], a2);
        a3 = fmaf(readlane_f(va, wb16 + r + 3), tp[(wb16 + r + 3) * TS + lane], a3);
      }
      fpart[s & 1][w][lane] = (a0 + a1) + (a2 + a3);
      elxc = __expf(slxn);                               // for step s+1, off path
      if (s + 2 <= TT - 1) slxn = slx[((s + 2) * BB + b) * SS + lane];
      ts = (ts == 2) ? 0 : ts + 1;
      BARRIER();
    }
    { // epilogue: alpha_{T-1}
      const int fs = (TT - 2) & 1;
      float S = (fpart[fs][0][lane] + fpart[fs][1][lane])
              + (fpart[fs][2][lane] + fpart[fs][3][lane]);
      u = elxc * fmaf(c, S, SEPS);
      c = __builtin_amdgcn_rcpf(wave_sum_dpp(u));
      if (w == 0) alpha[((TT - 1) * BB + b) * SS + lane] = u * c;
    }
  } else {
    // ==================== BACKWARD CONSUMERS ====================
    // breg kept in relative form (per-(t,b) shift drops in the q_z softmax);
    // renormalized by W each step so all values stay in [ln EPS, ~0].
    const int wb16 = __builtin_amdgcn_readfirstlane(w * 16);
    float breg = 0.f, rWc = 1.f;
    if (w == 0) log_beta[((TT - 1) * BB + b) * SS + lane] = 0.f;
    float slxc = slx[((TT - 1) * BB + b) * SS + lane];
    float mprev = 1.f;
    BARRIER();
    int ts = 0;
    for (int s = 0; s < TT - 1; ++s){
      if (s > 0){
        const int fs = (s - 1) & 1;
        float eh = (fpart[fs][0][lane] + fpart[fs][1][lane])
                 + (fpart[fs][2][lane] + fpart[fs][3][lane]);
        // v = log( sum_j tr_ij * wgt_j / W + EPS )  (shift-relative LSE)
        float v = __logf(fmaf(eh, rWc, EPSF));
        breg = (mprev == 1.0f) ? v : 0.0f;
        if (w == 0) log_beta[((TT - 1 - s) * BB + b) * SS + lane] = breg;
      }
      float wgt = __expf(slxc + breg);                   // lane = j
      float W = wave_sum_dpp(wgt);                       // overlaps matvec (VALU)
      rWc = __builtin_amdgcn_rcpf(W);                    // consumed next iter
      const float* __restrict__ tp = &tile[ts][lane * TS + wb16];
      float4 e0 = *(const float4*)(tp);
      float4 e1 = *(const float4*)(tp + 4);
      float4 e2 = *(const float4*)(tp + 8);
      float4 e3 = *(const float4*)(tp + 12);
      float a0 = 0.f, a1 = 0.f, a2 = 0.f, a3 = 0.f;
      a0 = fmaf(readlane_f(wgt, wb16 + 0),  e0.x, a0);
      a1 = fmaf(readlane_f(wgt, wb16 + 1),  e0.y, a1);
      a2 = fmaf(readlane_f(wgt, wb16 + 2),  e0.z, a2);
      a3 = fmaf(readlane_f(wgt, wb16 + 3),  e0.w, a3);
      a0 = fmaf(readlane_f(wgt, wb16 + 4),  e1.x, a0);
      a1 = fmaf(readlane_f(wgt, wb16 + 5),  e1.y, a1);
      a2 = fmaf(readlane_f(wgt, wb16 + 6),  e1.z, a2);
      a3 = fmaf(readlane_f(wgt, wb16 + 7),  e1.w, a3);
      a0 = fmaf(readlane_f(wgt, wb16 + 8),  e2.x, a0);
      a1 = fmaf(readlane_f(wgt, wb16 + 9),  e2.y, a1);
      a2 = fmaf(readlane_f(wgt, wb16 + 10), e2.z, a2);
      a3 = fmaf(readlane_f(wgt, wb16 + 11), e2.w, a3);
      a0 = fmaf(readlane_f(wgt, wb16 + 12), e3.x, a0);
      a1 = fmaf(readlane_f(wgt, wb16 + 13), e3.y, a1);
      a2 = fmaf(readlane_f(wgt, wb16 + 14), e3.z, a2);
      a3 = fmaf(readlane_f(wgt, wb16 + 15), e3.w, a3);
      fpart[s & 1][w][lane] = (a0 + a1) + (a2 + a3);
      mprev = mLDS[TT - 1 - s];
      if (s <= TT - 3) slxc = slx[((TT - 2 - s) * BB + b) * SS + lane];
      ts = (ts == 2) ? 0 : ts + 1;
      BARRIER();
    }
    { // epilogue: breg_0
      const int fs = (TT - 2) & 1;
      float eh = (fpart[fs][0][lane] + fpart[fs][1][lane])
               + (fpart[fs][2][lane] + fpart[fs][3][lane]);
      float v = __logf(fmaf(eh, rWc, EPSF));
      breg = (mprev == 1.0f) ? v : 0.0f;
      if (w == 0) log_beta[b * SS + lane] = breg;
    }
  }
}

// --- kernel 2 (fallback, verbatim previous version): fused scans with
// in-block tile generation. Used only when ws_size can't hold the tiles.
__global__ __launch_bounds__(768) void scan_kernel(
    const float* __restrict__ slx, const float* __restrict__ mask,
    const float* __restrict__ il, const float* __restrict__ a,
    const float* __restrict__ w_base, const float* __restrict__ w_act,
    float* __restrict__ alpha, float* __restrict__ log_beta){
  const int lane = threadIdx.x & 63;
  const int w    = threadIdx.x >> 6;
  const bool is_fwd = (blockIdx.x < BB);
  const int b = is_fwd ? blockIdx.x : (blockIdx.x - BB);

  __shared__ __align__(16) float tile[3][SS * TS];  // e_ij (unnormalized), [i][j]
  __shared__ float rsp[3][8][SS];                   // producer row-sum partials
  __shared__ float fpart[2][4][SS];                 // consumer matvec partials
  __shared__ __align__(16) float aLDS[TT * AA];     // a[:, b, :] staged
  __shared__ float mLDS[TT];                        // mask[:, b] staged

  for (int idx = threadIdx.x; idx < TT * AA; idx += 768){
    int t = idx >> 3, k = idx & 7;
    aLDS[idx] = a[(t * BB + b) * AA + k];
  }
  for (int idx = threadIdx.x; idx < TT; idx += 768)
    mLDS[idx] = mask[idx * BB + b];

  if (w >= 4){
    const int pw = w - 4;
    const int jb = pw * 8;
    float wb[8], wa[8][8];
    #pragma unroll
    for (int jj = 0; jj < 8; ++jj){
      wb[jj] = w_base[lane * SS + jb + jj];
      #pragma unroll
      for (int k = 0; k < 8; ++k)
        wa[k][jj] = w_act[(k * SS + lane) * SS + jb + jj];
    }
    float aa[8], aan[8];
    {
      const int t0 = is_fwd ? 0 : (TT - 2);
      const float* __restrict__ ap = a + (t0 * BB + b) * AA;
      #pragma unroll
      for (int k = 0; k < 8; ++k) aa[k] = ap[k];
      const int t1 = is_fwd ? 1 : (TT - 3);
      const float* __restrict__ ap1 = a + (t1 * BB + b) * AA;
      #pragma unroll
      for (int k = 0; k < 8; ++k) aan[k] = ap1[k];
    }
    {
      float ev[8]; float racc = 0.f;
      #pragma unroll
      for (int jj = 0; jj < 8; ++jj){
        float u = wb[jj];
        #pragma unroll
        for (int k = 0; k < 8; ++k) u = fmaf(aa[k], wa[k][jj], u);
        ev[jj] = __expf(u); racc += ev[jj];
      }
      *(float4*)&tile[0][lane * TS + jb]     = make_float4(ev[0],ev[1],ev[2],ev[3]);
      *(float4*)&tile[0][lane * TS + jb + 4] = make_float4(ev[4],ev[5],ev[6],ev[7]);
      rsp[0][pw][lane] = racc;
    }
    BARRIER();
    int tw = 1;
    for (int s = 0; s < TT - 1; ++s){
      if (s <= TT - 3){
        #pragma unroll
        for (int k = 0; k < 8; ++k) aa[k] = aan[k];
        if (s + 1 <= TT - 3){
          const int tn = is_fwd ? (s + 2) : (TT - 4 - s);
          #pragma unroll
          for (int k = 0; k < 8; ++k) aan[k] = aLDS[tn * AA + k];
        }
        float ev[8]; float racc = 0.f;
        #pragma unroll
        for (int jj = 0; jj < 8; ++jj){
          float u = wb[jj];
          #pragma unroll
          for (int k = 0; k < 8; ++k) u = fmaf(aa[k], wa[k][jj], u);
          ev[jj] = __expf(u); racc += ev[jj];
        }
        *(float4*)&tile[tw][lane * TS + jb]     = make_float4(ev[0],ev[1],ev[2],ev[3]);
        *(float4*)&tile[tw][lane * TS + jb + 4] = make_float4(ev[4],ev[5],ev[6],ev[7]);
        rsp[tw][pw][lane] = racc;
        tw = (tw == 2) ? 0 : tw + 1;
      }
      BARRIER();
    }
  } else if (is_fwd){
    const int wb16 = __builtin_amdgcn_readfirstlane(w * 16);
    float u = __expf(slx[b * SS + lane] + il[lane]);
    float c = __builtin_amdgcn_rcpf(wave_sum_dpp(u));
    if (w == 0) alpha[b * SS + lane] = u * c;
    float slxn = slx[(BB + b) * SS + lane];
    float elxc = 0.f;
    BARRIER();
    int ts = 0;
    for (int s = 0; s < TT - 1; ++s){
      if (s > 0){
        const int fs = (s - 1) & 1;
        float S = (fpart[fs][0][lane] + fpart[fs][1][lane])
                + (fpart[fs][2][lane] + fpart[fs][3][lane]);
        u = elxc * fmaf(c, S, SEPS);
        c = __builtin_amdgcn_rcpf(wave_sum_dpp(u));
        if (w == 0) alpha[(s * BB + b) * SS + lane] = u * c;
      }
      float rs = ((rsp[ts][0][lane] + rsp[ts][1][lane]) + (rsp[ts][2][lane] + rsp[ts][3][lane]))
               + ((rsp[ts][4][lane] + rsp[ts][5][lane]) + (rsp[ts][6][lane] + rsp[ts][7][lane]));
      float va = u * __builtin_amdgcn_rcpf(rs);
      const float* __restrict__ tp = &tile[ts][0];
      float a0 = 0.f, a1 = 0.f, a2 = 0.f, a3 = 0.f;
      #pragma unroll
      for (int r = 0; r < 16; r += 4){
        a0 = fmaf(readlane_f(va, wb16 + r    ), tp[(wb16 + r    ) * TS + lane], a0);
        a1 = fmaf(readlane_f(va, wb16 + r + 1), tp[(wb16 + r + 1) * TS + lane], a1);
        a2 = fmaf(readlane_f(va, wb16 + r + 2), tp[(wb16 + r + 2) * TS + lane], a2);
        a3 = fmaf(readlane_f(va, wb16 + r + 3), tp[(wb16 + r + 3) * TS + lane], a3);
      }
      fpart[s & 1][w][lane] = (a0 + a1) + (a2 + a3);
      elxc = __expf(slxn);
      if (s + 2 <= TT - 1) slxn = slx[((s + 2) * BB + b) * SS + lane];
      ts = (ts == 2) ? 0 : ts + 1;
      BARRIER();
    }
    {
      const int fs = (TT - 2) & 1;
      float S = (fpart[fs][0][lane] + fpart[fs][1][lane])
              + (fpart[fs][2][lane] + fpart[fs][3][lane]);
      u = elxc * fmaf(c, S, SEPS);
      c = __builtin_amdgcn_rcpf(wave_sum_dpp(u));
      if (w == 0) alpha[((TT - 1) * BB + b) * SS + lane] = u * c;
    }
  } else {
    const int wb16 = __builtin_amdgcn_readfirstlane(w * 16);
    float breg = 0.f, rWc = 1.f;
    if (w == 0) log_beta[((TT - 1) * BB + b) * SS + lane] = 0.f;
    float slxc = slx[((TT - 1) * BB + b) * SS + lane];
    float mprev = 1.f;
    BARRIER();
    int ts = 0, pts = 2;
    for (int s = 0; s < TT - 1; ++s){
      if (s > 0){
        const int fs = (s - 1) & 1;
        float eh = (fpart[fs][0][lane] + fpart[fs][1][lane])
                 + (fpart[fs][2][lane] + fpart[fs][3][lane]);
        float rsv = ((rsp[pts][0][lane] + rsp[pts][1][lane]) + (rsp[pts][2][lane] + rsp[pts][3][lane]))
                  + ((rsp[pts][4][lane] + rsp[pts][5][lane]) + (rsp[pts][6][lane] + rsp[pts][7][lane]));
        float v = __logf(fmaf(eh * __builtin_amdgcn_rcpf(rsv), rWc, EPSF));
        breg = (mprev == 1.0f) ? v : 0.0f;
        if (w == 0) log_beta[((TT - 1 - s) * BB + b) * SS + lane] = breg;
      }
      float wgt = __expf(slxc + breg);
      float W = wave_sum_dpp(wgt);
      rWc = __builtin_amdgcn_rcpf(W);
      const float* __restrict__ tp = &tile[ts][lane * TS + wb16];
      float4 e0 = *(const float4*)(tp);
      float4 e1 = *(const float4*)(tp + 4);
      float4 e2 = *(const float4*)(tp + 8);
      float4 e3 = *(const float4*)(tp + 12);
      float a0 = 0.f, a1 = 0.f, a2 = 0.f, a3 = 0.f;
      a0 = fmaf(readlane_f(wgt, wb16 + 0),  e0.x, a0);
      a1 = fmaf(readlane_f(wgt, wb16 + 1),  e0.y, a1);
      a2 = fmaf(readlane_f(wgt, wb16 + 2),  e0.z, a2);
      a3 = fmaf(readlane_f(wgt, wb16 + 3),  e0.w, a3);
      a0 = fmaf(readlane_f(wgt, wb16 + 4),  e1.x, a0);
      a1 = fmaf(readlane_f(wgt, wb16 + 5),  e1.y, a1);
      a2 = fmaf(readlane_f(wgt, wb16 + 6),  e1.z, a2);
      a3 = fmaf(readlane_f(wgt, wb16 + 7),  e1.w, a3);
      a0 = fmaf(readlane_f(wgt, wb16 + 8),  e2.x, a0);
      a1 = fmaf(readlane_f(wgt, wb16 + 9),  e2.y, a1);
      a2 = fmaf(readlane_f(wgt, wb16 + 10), e2.z, a2);
      a3 = fmaf(readlane_f(wgt, wb16 + 11), e2.w, a3);
      a0 = fmaf(readlane_f(wgt, wb16 + 12), e3.x, a0);
      a1 = fmaf(readlane_f(wgt, wb16 + 13), e3.y, a1);
      a2 = fmaf(readlane_f(wgt, wb16 + 14), e3.z, a2);
      a3 = fmaf(readlane_f(wgt, wb16 + 15), e3.w, a3);
      fpart[s & 1][w][lane] = (a0 + a1) + (a2 + a3);
      mprev = mLDS[TT - 1 - s];
      if (s <= TT - 3) slxc = slx[((TT - 2 - s) * BB + b) * SS + lane];
      pts = ts; ts = (ts == 2) ? 0 : ts + 1;
      BARRIER();
    }
    {
      const int fs = (TT - 2) & 1;
      float eh = (fpart[fs][0][lane] + fpart[fs][1][lane])
               + (fpart[fs][2][lane] + fpart[fs][3][lane]);
      float rsv = ((rsp[pts][0][lane] + rsp[pts][1][lane]) + (rsp[pts][2][lane] + rsp[pts][3][lane]))
                + ((rsp[pts][4][lane] + rsp[pts][5][lane]) + (rsp[pts][6][lane] + rsp[pts][7][lane]));
      float v = __logf(fmaf(eh * __builtin_amdgcn_rcpf(rsv), rWc, EPSF));
      breg = (mprev == 1.0f) ? v : 0.0f;
      if (w == 0) log_beta[b * SS + lane] = breg;
    }
  }
}

// --- kernel 3: q_z = softmax(log(alpha+EPS) + log_beta) over states
__global__ __launch_bounds__(256) void qz_kernel(
    const float* __restrict__ alpha, const float* __restrict__ log_beta,
    float* __restrict__ out){
  const int lane = threadIdx.x & 63;
  const int w = threadIdx.x >> 6;
  const int row = blockIdx.x * 4 + w;
  float v = __logf(alpha[row * SS + lane] + EPSF) + log_beta[row * SS + lane];
  float mx = wave_max(v);
  float e = __expf(v - mx);
  float sm = wave_sum(e);
  out[row * SS + lane] = e * __builtin_amdgcn_rcpf(sm);
}

extern "C" void kernel_launch(void* const* d_in, const int* in_sizes, int n_in,
                              void* d_out, int out_size, void* d_ws, size_t ws_size,
                              hipStream_t stream){
  const float* x      = (const float*)d_in[0];
  const float* a      = (const float*)d_in[1];
  const float* mask   = (const float*)d_in[2];
  const float* mu     = (const float*)d_in[3];
  const float* logv   = (const float*)d_in[4];
  const float* il     = (const float*)d_in[5];
  const float* w_base = (const float*)d_in[6];
  const float* w_act  = (const float*)d_in[7];
  float* out = (float*)d_out;

  float* ws = (float*)d_ws;
  const size_t TBS = (size_t)TT * BB * SS;
  float* iv       = ws;               // 2048 (+ cs, padded to 4096)
  float* cs       = ws + 2048;
  float* slx      = ws + 4096;        // TBS
  float* alpha    = slx + TBS;        // TBS
  float* log_beta = alpha + TBS;      // TBS
  float* trans    = log_beta + TBS;   // (TT-1)*BB*SS*SS = 268 MB (if it fits)

  const size_t TRANS_FLOATS = (size_t)(TT - 1) * BB * SS * SS;
  const size_t need_bytes = ((size_t)4096 + 3 * TBS + TRANS_FLOATS) * sizeof(float);

  prep_kernel<<<8, 256, 0, stream>>>(logv, iv, cs);
  logpx_kernel<<<TT * BB / 4, 256, 0, stream>>>(x, mu, iv, cs, slx);
  if (ws_size >= need_bytes){
    trans_kernel<<<512, 512, 0, stream>>>(a, w_base, w_act, trans);
    scan_pre_kernel<<<2 * BB, 512, 0, stream>>>(slx, mask, il, trans,
                                                alpha, log_beta);
  } else {
    scan_kernel<<<2 * BB, 768, 0, stream>>>(slx, mask, il, a, w_base, w_act,
                                            alpha, log_beta);
  }
  qz_kernel<<<TT * BB / 4, 256, 0, stream>>>(alpha, log_beta, out);
}